// Round 1
// baseline (833.162 us; speedup 1.0000x reference)
//
#include <hip/hip_runtime.h>
#include <stdint.h>
#include <stddef.h>

typedef short s16;
typedef __attribute__((ext_vector_type(8))) short short8;
typedef __attribute__((ext_vector_type(4))) float floatx4;

__device__ __forceinline__ float bf2f(short s) {
    union { float f; uint32_t u; } c; c.u = ((uint32_t)(uint16_t)s) << 16; return c.f;
}
__device__ __forceinline__ short f2bf(float f) {
    union { float f; uint32_t u; } c; c.f = f;
    uint32_t u = c.u;
    u += 0x7fffu + ((u >> 16) & 1u);   // RNE
    return (short)(u >> 16);
}

// ---------------- K_cvt: x fp32 -> bf16 (8 elem / thread) ----------------
__global__ __launch_bounds__(256) void cvt_kernel(const float* __restrict__ src,
                                                  s16* __restrict__ dst) {
    size_t i = (size_t)blockIdx.x * 256 + threadIdx.x;
    const floatx4* s4 = (const floatx4*)src;
    floatx4 a = s4[i * 2], b = s4[i * 2 + 1];
    short8 o;
    o[0] = f2bf(a[0]); o[1] = f2bf(a[1]); o[2] = f2bf(a[2]); o[3] = f2bf(a[3]);
    o[4] = f2bf(b[0]); o[5] = f2bf(b[1]); o[6] = f2bf(b[2]); o[7] = f2bf(b[3]);
    ((short8*)dst)[i] = o;
}

// ------------- K0: transpose weight fp32 (K,N) -> bf16 (N,K) -------------
__global__ __launch_bounds__(256) void transpose_kernel(const float* __restrict__ w,
                                                        s16* __restrict__ wt,
                                                        int K, int N) {
    int idx = blockIdx.x * 256 + threadIdx.x;
    if (idx >= K * N) return;
    int n = idx / K, k = idx - n * K;      // wt[n][k] = w[k][n]; writes coalesced
    wt[idx] = f2bf(w[(size_t)k * N + n]);
}

// row m (0..100351) -> pointer to its 512-ch row inside x (window gather)
__device__ __forceinline__ const s16* x_row_ptr(const s16* xb, int m) {
    int win = m / 49, t = m - win * 49;
    int b = win >> 6, rem = win & 63, hb = rem >> 3, wb = rem & 7;
    int r = t / 7, c = t - r * 7;
    int n = (hb * 7 + r) * 56 + wb * 7 + c;
    return xb + ((size_t)b * 3136 + n) * 512;
}

// ---------------------------------------------------------------------------
// GEMM: 256x128 tile, BK=64, 16x16x32 bf16 MFMA, 512 threads (8 waves, 4Mx2N).
// 3-deep LDS pipeline (144 KiB): while computing K-step kt from buf[kt%3],
// K-step kt+2 is staged into buf[(kt+2)%3] (last read at kt-1, barrier-done).
// Counted vmcnt: 6 global_load_lds per thread per K-step -> 12 in flight at a
// boundary; s_waitcnt vmcnt(6) drains exactly the next step's loads, never 0
// until the tail (T3+T4). Raw s_barrier (NOT __syncthreads -> would vmcnt(0)),
// sched_barrier(0) pins compiler motion across the boundary. setprio around
// the MFMA cluster (T5). XOR-swizzled LDS (verified 0 bank conflicts): slot
// (row, c) holds global k-block (c ^ (row&7)); global_load_lds dest stays
// linear, source column is pre-swizzled per lane.
// XCD-chunked bijective swizzle: 12 (resp 4) consecutive tile-ids share one
// A-panel -> same XCD L2 (T1).
// MODE 0: A = xbf (window gather), N=1536, out = qkv bf16 (m,1536)
// MODE 1: A = attn (contiguous),   N=512,  out = d_out fp32 (window scatter)
// ---------------------------------------------------------------------------
template <int MODE>
__global__ __launch_bounds__(512, 2) void gemm_kernel(const s16* __restrict__ A,
                                                      const s16* __restrict__ Bt,
                                                      const float* __restrict__ bias,
                                                      void* __restrict__ outp) {
    constexpr int NT  = (MODE == 0) ? 12 : 4;     // N / 128
    constexpr int CPX = (MODE == 0) ? 588 : 196;  // gridDim.x / 8

    // hardware id f runs on XCD f&7 -> give each XCD a contiguous tile range
    const int o  = (blockIdx.x & 7) * CPX + (blockIdx.x >> 3);
    const int tm = o / NT, tn = o - tm * NT;

    const int tid = threadIdx.x, wave = tid >> 6, lane = tid & 63;

    __shared__ s16 lA[3][256 * 64];   // 96 KiB, (row, k) xor-swizzled
    __shared__ s16 lB[3][128 * 64];   // 48 KiB

    // staging: chunk = 8 rows x 64 k (1 KiB); wave covers 4 A-chunks, 2 B-chunks
    const int sub  = lane >> 3;                    // row within chunk
    const int col8 = (((lane & 7) ^ sub) << 3);    // swizzled source k-block
    const s16* a_src[4];
    const s16* b_src[2];
#pragma unroll
    for (int i = 0; i < 4; ++i) {
        int row = (wave * 4 + i) * 8 + sub;        // 0..255
        if (MODE == 0) a_src[i] = x_row_ptr(A, tm * 256 + row) + col8;
        else           a_src[i] = A + (size_t)(tm * 256 + row) * 512 + col8;
    }
#pragma unroll
    for (int i = 0; i < 2; ++i) {
        int row = (wave * 2 + i) * 8 + sub;        // 0..127
        b_src[i] = Bt + (size_t)(tn * 128 + row) * 512 + col8;
    }

#define STAGE(buf)                                                              \
    do {                                                                        \
        _Pragma("unroll")                                                       \
        for (int i_ = 0; i_ < 4; ++i_) {                                        \
            __builtin_amdgcn_global_load_lds(                                   \
                (const __attribute__((address_space(1))) void*)a_src[i_],       \
                (__attribute__((address_space(3))) void*)&lA[buf][(wave * 4 + i_) * 512], \
                16, 0, 0);                                                      \
            a_src[i_] += 64;                                                    \
        }                                                                       \
        _Pragma("unroll")                                                       \
        for (int i_ = 0; i_ < 2; ++i_) {                                        \
            __builtin_amdgcn_global_load_lds(                                   \
                (const __attribute__((address_space(1))) void*)b_src[i_],       \
                (__attribute__((address_space(3))) void*)&lB[buf][(wave * 2 + i_) * 512], \
                16, 0, 0);                                                      \
            b_src[i_] += 64;                                                    \
        }                                                                       \
    } while (0)

    floatx4 acc[4][4];
#pragma unroll
    for (int mt = 0; mt < 4; ++mt)
#pragma unroll
        for (int nt = 0; nt < 4; ++nt)
            acc[mt][nt] = (floatx4){0.f, 0.f, 0.f, 0.f};

    const int wm = wave >> 1, wn = wave & 1;       // 4M x 2N wave grid
    const int lm = lane & 15, quad = lane >> 4;

    // prologue: fill pipeline 2 deep
    STAGE(0);
    STAGE(1);
    asm volatile("s_waitcnt vmcnt(6)" ::: "memory");   // kt0 resident, kt1 in flight
    __builtin_amdgcn_s_barrier();
    __builtin_amdgcn_sched_barrier(0);

#pragma unroll
    for (int kt = 0; kt < 8; ++kt) {
        if (kt + 2 < 8) STAGE((kt + 2) % 3);           // issue-early prefetch
        const int cur = kt % 3;

        short8 af[4][2], bq[4][2];                     // each fragment read ONCE
#pragma unroll
        for (int kk = 0; kk < 2; ++kk) {
            const int sw = (((kk << 2) | quad) ^ (lm & 7)) << 3;
#pragma unroll
            for (int mt = 0; mt < 4; ++mt)
                af[mt][kk] = *(const short8*)&lA[cur][(wm * 64 + mt * 16 + lm) * 64 + sw];
#pragma unroll
            for (int nt = 0; nt < 4; ++nt)
                bq[nt][kk] = *(const short8*)&lB[cur][(wn * 64 + nt * 16 + lm) * 64 + sw];
        }

        __builtin_amdgcn_s_setprio(1);
#pragma unroll
        for (int kk = 0; kk < 2; ++kk)
#pragma unroll
            for (int mt = 0; mt < 4; ++mt)
#pragma unroll
                for (int nt = 0; nt < 4; ++nt)
                    acc[mt][nt] = __builtin_amdgcn_mfma_f32_16x16x32_bf16(
                        af[mt][kk], bq[nt][kk], acc[mt][nt], 0, 0, 0);
        __builtin_amdgcn_s_setprio(0);

        if (kt < 7) {
            if (kt < 6) asm volatile("s_waitcnt vmcnt(6)" ::: "memory"); // drain kt+1 only
            else        asm volatile("s_waitcnt vmcnt(0)" ::: "memory"); // tail: kt7
            __builtin_amdgcn_s_barrier();
            __builtin_amdgcn_sched_barrier(0);
        }
    }
#undef STAGE

    // ---- epilogue: C/D layout col = lane&15, row = quad*4 + reg ----
    float bv[4];
#pragma unroll
    for (int nt = 0; nt < 4; ++nt)
        bv[nt] = bias[tn * 128 + wn * 64 + nt * 16 + lm];

#pragma unroll
    for (int mt = 0; mt < 4; ++mt) {
        int mbase = tm * 256 + wm * 64 + mt * 16 + quad * 4;
#pragma unroll
        for (int i = 0; i < 4; ++i) {
            int m = mbase + i;
            size_t rowoff;
            if (MODE == 1) {
                int win = m / 49, t = m - win * 49;
                int b = win >> 6, rem = win & 63, hb = rem >> 3, wb = rem & 7;
                int r = t / 7, c = t - r * 7;
                int n = (hb * 7 + r) * 56 + wb * 7 + c;
                rowoff = ((size_t)b * 3136 + n) * 512;
            } else {
                rowoff = (size_t)m * 1536;
            }
#pragma unroll
            for (int nt = 0; nt < 4; ++nt) {
                int coln = tn * 128 + wn * 64 + nt * 16 + lm;
                float v = acc[mt][nt][i] + bv[nt];
                if (MODE == 0) ((s16*)outp)[rowoff + coln] = f2bf(v);
                else           ((float*)outp)[rowoff + coln] = v;
            }
        }
    }
}

// --------- K2: per-(win,token) 8x8 head attention; 1 wave / row ----------
// qkv row m: [0,512)=q (h*64+d), [512,1024)=k, [1024,1536)=v
// out layout: attn[win*25088 + h*3136 + t*64 + d]  (== (m,512) rows for proj)
__global__ __launch_bounds__(256) void attn_kernel(const s16* __restrict__ qkv,
                                                   s16* __restrict__ attn) {
    const int tid = threadIdx.x, wave = tid >> 6, lane = tid & 63;
    const int m = blockIdx.x * 4 + wave;   // grid 25088 * 4 = 100352 exact

    __shared__ s16 sh[4][1536];
    s16* my = sh[wave];
    const s16* row = qkv + (size_t)m * 1536;
#pragma unroll
    for (int i = 0; i < 3; ++i)
        *(short8*)&my[i * 512 + lane * 8] = *(const short8*)&row[i * 512 + lane * 8];
    __syncthreads();

    const int h = lane >> 3, g = lane & 7;
    const s16* qs = my + h * 64;
    const s16* ks = my + 512 + g * 64;
    const s16* vs = my + 1024;

    // S[h][g] = (q_h . k_g) / 8 ; d-rotation by h avoids LDS bank conflicts
    float s = 0.f;
#pragma unroll
    for (int db = 0; db < 8; ++db) {
        int d0 = ((db + h) & 7) * 8;
        short8 q8 = *(const short8*)&qs[d0];
        short8 k8 = *(const short8*)&ks[d0];
#pragma unroll
        for (int j = 0; j < 8; ++j) s += bf2f(q8[j]) * bf2f(k8[j]);
    }
    s *= 0.125f;

    // softmax over g within each 8-lane group
    float mx = s;
    mx = fmaxf(mx, __shfl_xor(mx, 1));
    mx = fmaxf(mx, __shfl_xor(mx, 2));
    mx = fmaxf(mx, __shfl_xor(mx, 4));
    float p = __expf(s - mx);
    float sum = p;
    sum += __shfl_xor(sum, 1);
    sum += __shfl_xor(sum, 2);
    sum += __shfl_xor(sum, 4);
    p /= sum;

    // O[h][d0..d0+7], d0 = (lane&7)*8 ; p[h][gg] lives in lane h*8+gg
    float o[8];
#pragma unroll
    for (int j = 0; j < 8; ++j) o[j] = 0.f;
    const int dgrp = (lane & 7) * 8;
#pragma unroll
    for (int gg = 0; gg < 8; ++gg) {
        float pg = __shfl(p, h * 8 + gg);
        short8 v8 = *(const short8*)&vs[gg * 64 + dgrp];
#pragma unroll
        for (int j = 0; j < 8; ++j) o[j] += pg * bf2f(v8[j]);
    }

    int win = m / 49, t = m - win * 49;
    s16* dst = attn + (size_t)win * 25088 + h * 3136 + t * 64 + dgrp;
    short8 ob;
#pragma unroll
    for (int j = 0; j < 8; ++j) ob[j] = f2bf(o[j]);
    *(short8*)dst = ob;
}

extern "C" void kernel_launch(void* const* d_in, const int* in_sizes, int n_in,
                              void* d_out, int out_size, void* d_ws, size_t ws_size,
                              hipStream_t stream) {
    const float* x      = (const float*)d_in[0];
    const float* w_qkv  = (const float*)d_in[1];
    const float* b_qkv  = (const float*)d_in[2];
    const float* w_proj = (const float*)d_in[3];
    const float* b_proj = (const float*)d_in[4];

    char* ws = (char*)d_ws;
    // 102,760,448 B = 100352*512*2 ; 308,281,344 B = 100352*1536*2
    s16* xbf    = (s16*)ws;
    s16* qkv    = (s16*)(ws + 102760448ull);
    s16* attn   = (s16*)(ws + 102760448ull + 308281344ull);
    s16* wqkvT  = (s16*)(ws + 102760448ull + 308281344ull + 102760448ull);
    s16* wprojT = (s16*)(ws + 102760448ull + 308281344ull + 102760448ull + 1572864ull);

    cvt_kernel<<<25088, 256, 0, stream>>>(x, xbf);                       // 51.4M elems
    transpose_kernel<<<3072, 256, 0, stream>>>(w_qkv, wqkvT, 512, 1536);
    transpose_kernel<<<1024, 256, 0, stream>>>(w_proj, wprojT, 512, 512);
    gemm_kernel<0><<<392 * 12, 512, 0, stream>>>(xbf, wqkvT, b_qkv, qkv);
    attn_kernel<<<25088, 256, 0, stream>>>(qkv, attn);
    gemm_kernel<1><<<392 * 4, 512, 0, stream>>>(attn, wprojT, b_proj, d_out);
}

// Round 2
// 759.884 us; speedup vs baseline: 1.0964x; 1.0964x over previous
//
#include <hip/hip_runtime.h>
#include <stdint.h>
#include <stddef.h>

typedef short s16;
typedef __attribute__((ext_vector_type(8))) short short8;
typedef __attribute__((ext_vector_type(4))) float floatx4;

__device__ __forceinline__ float bf2f(short s) {
    union { float f; uint32_t u; } c; c.u = ((uint32_t)(uint16_t)s) << 16; return c.f;
}
__device__ __forceinline__ short f2bf(float f) {
    union { float f; uint32_t u; } c; c.f = f;
    uint32_t u = c.u;
    u += 0x7fffu + ((u >> 16) & 1u);   // RNE
    return (short)(u >> 16);
}

// ---------------- K_cvt: x fp32 -> bf16 (8 elem / thread) ----------------
__global__ __launch_bounds__(256) void cvt_kernel(const float* __restrict__ src,
                                                  s16* __restrict__ dst) {
    size_t i = (size_t)blockIdx.x * 256 + threadIdx.x;
    const floatx4* s4 = (const floatx4*)src;
    floatx4 a = s4[i * 2], b = s4[i * 2 + 1];
    short8 o;
    o[0] = f2bf(a[0]); o[1] = f2bf(a[1]); o[2] = f2bf(a[2]); o[3] = f2bf(a[3]);
    o[4] = f2bf(b[0]); o[5] = f2bf(b[1]); o[6] = f2bf(b[2]); o[7] = f2bf(b[3]);
    ((short8*)dst)[i] = o;
}

// ------------- K0: transpose weight fp32 (K,N) -> bf16 (N,K) -------------
__global__ __launch_bounds__(256) void transpose_kernel(const float* __restrict__ w,
                                                        s16* __restrict__ wt,
                                                        int K, int N) {
    int idx = blockIdx.x * 256 + threadIdx.x;
    if (idx >= K * N) return;
    int n = idx / K, k = idx - n * K;      // wt[n][k] = w[k][n]; writes coalesced
    wt[idx] = f2bf(w[(size_t)k * N + n]);
}

// row m (0..100351) -> pointer to its 512-ch row inside x (window gather)
__device__ __forceinline__ const s16* x_row_ptr(const s16* xb, int m) {
    int win = m / 49, t = m - win * 49;
    int b = win >> 6, rem = win & 63, hb = rem >> 3, wb = rem & 7;
    int r = t / 7, c = t - r * 7;
    int n = (hb * 7 + r) * 56 + wb * 7 + c;
    return xb + ((size_t)b * 3136 + n) * 512;
}

// ---------------------------------------------------------------------------
// GEMM: 256x256 tile, BK=32, 16x16x32 bf16 MFMA, 512 threads (8 waves).
// Wave tile 128x64: wm=wave&1 (A half), wn=wave>>1 (B quarter). acc[8][4].
// 3 LDS buffers (96 KiB): compute kt from buf[kt%3], stage kt+2 into
// buf[(kt+2)%3] (last read at kt-1; those reads are fenced by that phase's
// lgkmcnt(0) before its end barrier -> no write/read race).
// 4 phases per K-step (T3): phase p = { ds_read mt-pair p (+ all bq at p0),
// issue 1 global_load_lds of kt+2, s_barrier, lgkmcnt(0)+sched_barrier,
// setprio(1), 8 MFMA, setprio(0), [vmcnt(4) at p3], s_barrier }.
// Counted vmcnt (T4): at each K-step boundary exactly kt+2's 4 loads stay in
// flight; kt+1 is guaranteed resident. vmcnt(0) only at kt=14 (tail).
// No swizzle needed: BK=32 -> 64 B row stride -> a wave's b128 fragment read
// touches each bank exactly 8x = the 1024B/(128B/cyc) minimum (T2's >=128B
// stride prerequisite doesn't hold).
// XCD-chunked bijective swizzle (T1): NT consecutive tiles share an A panel.
// MODE 0: A = xbf (window gather), N=1536, out = qkv bf16 (m,1536)
// MODE 1: A = attn (contiguous),   N=512,  out = d_out fp32 (window scatter)
// ---------------------------------------------------------------------------
template <int MODE>
__global__ __launch_bounds__(512, 2) void gemm_kernel(const s16* __restrict__ A,
                                                      const s16* __restrict__ Bt,
                                                      const float* __restrict__ bias,
                                                      void* __restrict__ outp) {
    constexpr int NT  = (MODE == 0) ? 6 : 2;      // N / 256
    constexpr int CPX = (MODE == 0) ? 294 : 98;   // gridDim.x / 8

    const int o  = (blockIdx.x & 7) * CPX + (blockIdx.x >> 3);
    const int tm = o / NT, tn = o - tm * NT;

    const int tid = threadIdx.x, wave = tid >> 6, lane = tid & 63;

    __shared__ s16 lA[3][256 * 32];   // 48 KiB: [row][k], 64 B rows
    __shared__ s16 lB[3][256 * 32];   // 48 KiB

    // staging: half-tile = 128 rows x 32 k = 8 KiB = 1 load-round (512 x 16 B)
    const int rloc = wave * 16 + (lane >> 2);    // row within half-tile 0..127
    const int gran = (lane & 3) * 8;             // s16 offset within 32-k row
    const s16* a_src[2];
    const s16* b_src[2];
#pragma unroll
    for (int i = 0; i < 2; ++i) {
        int row = i * 128 + rloc;
        if (MODE == 0) a_src[i] = x_row_ptr(A, tm * 256 + row) + gran;
        else           a_src[i] = A + (size_t)(tm * 256 + row) * 512 + gran;
        b_src[i] = Bt + (size_t)(tn * 256 + row) * 512 + gran;
    }

#define STAGE_A(buf, i)                                                         \
    do {                                                                        \
        __builtin_amdgcn_global_load_lds(                                       \
            (const __attribute__((address_space(1))) void*)a_src[i],            \
            (__attribute__((address_space(3))) void*)&lA[buf][(i) * 4096 + wave * 512], \
            16, 0, 0);                                                          \
        a_src[i] += 32;                                                         \
    } while (0)
#define STAGE_B(buf, i)                                                         \
    do {                                                                        \
        __builtin_amdgcn_global_load_lds(                                       \
            (const __attribute__((address_space(1))) void*)b_src[i],            \
            (__attribute__((address_space(3))) void*)&lB[buf][(i) * 4096 + wave * 512], \
            16, 0, 0);                                                          \
        b_src[i] += 32;                                                         \
    } while (0)

    floatx4 acc[8][4];
#pragma unroll
    for (int mt = 0; mt < 8; ++mt)
#pragma unroll
        for (int nt = 0; nt < 4; ++nt)
            acc[mt][nt] = (floatx4){0.f, 0.f, 0.f, 0.f};

    const int wm = wave & 1, wn = wave >> 1;     // A half, B quarter
    const int lm = lane & 15, quad = lane >> 4;
    const int koff = quad * 8;                   // k offset of fragment (s16)

    // prologue: stage kt=0 and kt=1 (8 loads/wave), wait until kt0 resident
    STAGE_A(0, 0); STAGE_A(0, 1); STAGE_B(0, 0); STAGE_B(0, 1);
    STAGE_A(1, 0); STAGE_A(1, 1); STAGE_B(1, 0); STAGE_B(1, 1);
    asm volatile("s_waitcnt vmcnt(4)" ::: "memory");
    __builtin_amdgcn_s_barrier();
    __builtin_amdgcn_sched_barrier(0);

#pragma unroll
    for (int kt = 0; kt < 16; ++kt) {
        const int cur = kt % 3, nxt = (kt + 2) % 3;
        short8 bq[4];
#pragma unroll
        for (int p = 0; p < 4; ++p) {
            // --- ds reads for this phase ---
            if (p == 0) {
#pragma unroll
                for (int nt = 0; nt < 4; ++nt)
                    bq[nt] = *(const short8*)&lB[cur][(wn * 64 + nt * 16 + lm) * 32 + koff];
            }
            short8 a0 = *(const short8*)&lA[cur][(wm * 128 + (2 * p) * 16 + lm) * 32 + koff];
            short8 a1 = *(const short8*)&lA[cur][(wm * 128 + (2 * p + 1) * 16 + lm) * 32 + koff];

            // --- issue exactly one prefetch load for kt+2 ---
            if (kt < 14) {
                if      (p == 0) STAGE_A(nxt, 0);
                else if (p == 1) STAGE_A(nxt, 1);
                else if (p == 2) STAGE_B(nxt, 0);
                else             STAGE_B(nxt, 1);
            }

            __builtin_amdgcn_s_barrier();
            asm volatile("s_waitcnt lgkmcnt(0)" ::: "memory");
            __builtin_amdgcn_sched_barrier(0);

            __builtin_amdgcn_s_setprio(1);
#pragma unroll
            for (int nt = 0; nt < 4; ++nt)
                acc[2 * p][nt] = __builtin_amdgcn_mfma_f32_16x16x32_bf16(
                    a0, bq[nt], acc[2 * p][nt], 0, 0, 0);
#pragma unroll
            for (int nt = 0; nt < 4; ++nt)
                acc[2 * p + 1][nt] = __builtin_amdgcn_mfma_f32_16x16x32_bf16(
                    a1, bq[nt], acc[2 * p + 1][nt], 0, 0, 0);
            __builtin_amdgcn_s_setprio(0);

            if (p == 3) {
                if (kt < 14)       asm volatile("s_waitcnt vmcnt(4)" ::: "memory");
                else if (kt == 14) asm volatile("s_waitcnt vmcnt(0)" ::: "memory");
            }
            if (!(kt == 15 && p == 3)) {
                __builtin_amdgcn_s_barrier();
                __builtin_amdgcn_sched_barrier(0);
            }
        }
    }
#undef STAGE_A
#undef STAGE_B

    // ---- epilogue: C/D layout col = lane&15, row = quad*4 + reg ----
    float bv[4];
#pragma unroll
    for (int nt = 0; nt < 4; ++nt)
        bv[nt] = bias[tn * 256 + wn * 64 + nt * 16 + lm];

#pragma unroll
    for (int mt = 0; mt < 8; ++mt) {
        int mbase = tm * 256 + wm * 128 + mt * 16 + quad * 4;
#pragma unroll
        for (int i = 0; i < 4; ++i) {
            int m = mbase + i;
            size_t rowoff;
            if (MODE == 1) {
                int win = m / 49, t = m - win * 49;
                int b = win >> 6, rem = win & 63, hb = rem >> 3, wb = rem & 7;
                int r = t / 7, c = t - r * 7;
                int n = (hb * 7 + r) * 56 + wb * 7 + c;
                rowoff = ((size_t)b * 3136 + n) * 512;
            } else {
                rowoff = (size_t)m * 1536;
            }
#pragma unroll
            for (int nt = 0; nt < 4; ++nt) {
                int coln = tn * 256 + wn * 64 + nt * 16 + lm;
                float v = acc[mt][nt][i] + bv[nt];
                if (MODE == 0) ((s16*)outp)[rowoff + coln] = f2bf(v);
                else           ((float*)outp)[rowoff + coln] = v;
            }
        }
    }
}

// --------- K2: per-(win,token) 8x8 head attention; 1 wave / row ----------
// qkv row m: [0,512)=q (h*64+d), [512,1024)=k, [1024,1536)=v
// out layout: attn[win*25088 + h*3136 + t*64 + d]  (== (m,512) rows for proj)
__global__ __launch_bounds__(256) void attn_kernel(const s16* __restrict__ qkv,
                                                   s16* __restrict__ attn) {
    const int tid = threadIdx.x, wave = tid >> 6, lane = tid & 63;
    const int m = blockIdx.x * 4 + wave;   // grid 25088 * 4 = 100352 exact

    __shared__ s16 sh[4][1536];
    s16* my = sh[wave];
    const s16* row = qkv + (size_t)m * 1536;
#pragma unroll
    for (int i = 0; i < 3; ++i)
        *(short8*)&my[i * 512 + lane * 8] = *(const short8*)&row[i * 512 + lane * 8];
    __syncthreads();

    const int h = lane >> 3, g = lane & 7;
    const s16* qs = my + h * 64;
    const s16* ks = my + 512 + g * 64;
    const s16* vs = my + 1024;

    // S[h][g] = (q_h . k_g) / 8 ; d-rotation by h avoids LDS bank conflicts
    float s = 0.f;
#pragma unroll
    for (int db = 0; db < 8; ++db) {
        int d0 = ((db + h) & 7) * 8;
        short8 q8 = *(const short8*)&qs[d0];
        short8 k8 = *(const short8*)&ks[d0];
#pragma unroll
        for (int j = 0; j < 8; ++j) s += bf2f(q8[j]) * bf2f(k8[j]);
    }
    s *= 0.125f;

    // softmax over g within each 8-lane group
    float mx = s;
    mx = fmaxf(mx, __shfl_xor(mx, 1));
    mx = fmaxf(mx, __shfl_xor(mx, 2));
    mx = fmaxf(mx, __shfl_xor(mx, 4));
    float p = __expf(s - mx);
    float sum = p;
    sum += __shfl_xor(sum, 1);
    sum += __shfl_xor(sum, 2);
    sum += __shfl_xor(sum, 4);
    p /= sum;

    // O[h][d0..d0+7], d0 = (lane&7)*8 ; p[h][gg] lives in lane h*8+gg
    float o[8];
#pragma unroll
    for (int j = 0; j < 8; ++j) o[j] = 0.f;
    const int dgrp = (lane & 7) * 8;
#pragma unroll
    for (int gg = 0; gg < 8; ++gg) {
        float pg = __shfl(p, h * 8 + gg);
        short8 v8 = *(const short8*)&vs[gg * 64 + dgrp];
#pragma unroll
        for (int j = 0; j < 8; ++j) o[j] += pg * bf2f(v8[j]);
    }

    int win = m / 49, t = m - win * 49;
    s16* dst = attn + (size_t)win * 25088 + h * 3136 + t * 64 + dgrp;
    short8 ob;
#pragma unroll
    for (int j = 0; j < 8; ++j) ob[j] = f2bf(o[j]);
    *(short8*)dst = ob;
}

extern "C" void kernel_launch(void* const* d_in, const int* in_sizes, int n_in,
                              void* d_out, int out_size, void* d_ws, size_t ws_size,
                              hipStream_t stream) {
    const float* x      = (const float*)d_in[0];
    const float* w_qkv  = (const float*)d_in[1];
    const float* b_qkv  = (const float*)d_in[2];
    const float* w_proj = (const float*)d_in[3];
    const float* b_proj = (const float*)d_in[4];

    char* ws = (char*)d_ws;
    // 102,760,448 B = 100352*512*2 ; 308,281,344 B = 100352*1536*2
    s16* xbf    = (s16*)ws;
    s16* qkv    = (s16*)(ws + 102760448ull);
    s16* attn   = (s16*)(ws + 102760448ull + 308281344ull);
    s16* wqkvT  = (s16*)(ws + 102760448ull + 308281344ull + 102760448ull);
    s16* wprojT = (s16*)(ws + 102760448ull + 308281344ull + 102760448ull + 1572864ull);

    cvt_kernel<<<25088, 256, 0, stream>>>(x, xbf);                       // 51.4M elems
    transpose_kernel<<<3072, 256, 0, stream>>>(w_qkv, wqkvT, 512, 1536);
    transpose_kernel<<<1024, 256, 0, stream>>>(w_proj, wprojT, 512, 512);
    gemm_kernel<0><<<392 * 6, 512, 0, stream>>>(xbf, wqkvT, b_qkv, qkv);
    attn_kernel<<<25088, 256, 0, stream>>>(qkv, attn);
    gemm_kernel<1><<<392 * 2, 512, 0, stream>>>(attn, wprojT, b_proj, d_out);
}

// Round 3
// 714.098 us; speedup vs baseline: 1.1667x; 1.0641x over previous
//
#include <hip/hip_runtime.h>
#include <stdint.h>
#include <stddef.h>

typedef short s16;
typedef __attribute__((ext_vector_type(8))) short short8;
typedef __attribute__((ext_vector_type(4))) float floatx4;

__device__ __forceinline__ float bf2f(short s) {
    union { float f; uint32_t u; } c; c.u = ((uint32_t)(uint16_t)s) << 16; return c.f;
}
__device__ __forceinline__ short f2bf(float f) {
    union { float f; uint32_t u; } c; c.f = f;
    uint32_t u = c.u;
    u += 0x7fffu + ((u >> 16) & 1u);   // RNE
    return (short)(u >> 16);
}

// ---------------- K_cvt: x fp32 -> bf16 (8 elem / thread) ----------------
__global__ __launch_bounds__(256) void cvt_kernel(const float* __restrict__ src,
                                                  s16* __restrict__ dst) {
    size_t i = (size_t)blockIdx.x * 256 + threadIdx.x;
    const floatx4* s4 = (const floatx4*)src;
    floatx4 a = s4[i * 2], b = s4[i * 2 + 1];
    short8 o;
    o[0] = f2bf(a[0]); o[1] = f2bf(a[1]); o[2] = f2bf(a[2]); o[3] = f2bf(a[3]);
    o[4] = f2bf(b[0]); o[5] = f2bf(b[1]); o[6] = f2bf(b[2]); o[7] = f2bf(b[3]);
    ((short8*)dst)[i] = o;
}

// ------------- K0: transpose weight fp32 (K,N) -> bf16 (N,K) -------------
__global__ __launch_bounds__(256) void transpose_kernel(const float* __restrict__ w,
                                                        s16* __restrict__ wt,
                                                        int K, int N) {
    int idx = blockIdx.x * 256 + threadIdx.x;
    if (idx >= K * N) return;
    int n = idx / K, k = idx - n * K;      // wt[n][k] = w[k][n]; writes coalesced
    wt[idx] = f2bf(w[(size_t)k * N + n]);
}

// row m (0..100351) -> pointer to its 512-ch row inside x (window gather)
__device__ __forceinline__ const s16* x_row_ptr(const s16* xb, int m) {
    int win = m / 49, t = m - win * 49;
    int b = win >> 6, rem = win & 63, hb = rem >> 3, wb = rem & 7;
    int r = t / 7, c = t - r * 7;
    int n = (hb * 7 + r) * 56 + wb * 7 + c;
    return xb + ((size_t)b * 3136 + n) * 512;
}

// ---------------------------------------------------------------------------
// GEMM: 256x256 tile, BK=32, 16x16x32 bf16 MFMA, 512 threads (8 waves).
// Wave tile 128x64: wm=wave&1 (A half), wn=wave>>1 (B quarter). acc[8][4].
// 3 LDS buffers (96 KiB): compute kt from buf[kt%3], stage kt+2 into
// buf[(kt+2)%3] (last read at kt-1; reads fenced by lgkmcnt(0) before that
// K-step's end barrier -> no write/read race).
// LDS slot swizzle (T2 for 64 B rows): slot s of row r holds global k-block
// s ^ ((r>>1)&3). Staging keeps the LDS dest LINEAR (global_load_lds
// requirement) and pre-swizzles the per-lane SOURCE k-offset; fragment reads
// use slot quad ^ ((lm>>1)&3). Every consecutive 8-lane group then covers all
// 8 distinct 16 B slots (= all 32 banks) -> conflict-free. Round-2 unswizzled
// layout measured 1.45e7 SQ_LDS_BANK_CONFLICT (4-way on every b128).
// 2 phases per K-step, 16 MFMA each (m201 granularity): phase p = { ds_read
// 4 A-frags (+4 B-frags at p0), issue 2 global_load_lds of kt+2, s_barrier,
// lgkmcnt(0)+sched_barrier, setprio(1), 16 MFMA, setprio(0),
// [p1: counted vmcnt], s_barrier }.
// Counted vmcnt (T4): 4 loads/K-step; at each K-step boundary vmcnt(4) leaves
// exactly kt+2's loads in flight, kt+1 guaranteed resident. vmcnt(0) only at
// kt=14 (tail).
// XCD-chunked bijective swizzle (T1): NT consecutive tiles share an A panel.
// MODE 0: A = xbf (window gather), N=1536, out = qkv bf16 (m,1536)
// MODE 1: A = attn (contiguous),   N=512,  out = d_out fp32 (window scatter)
// ---------------------------------------------------------------------------
template <int MODE>
__global__ __launch_bounds__(512, 2) void gemm_kernel(const s16* __restrict__ A,
                                                      const s16* __restrict__ Bt,
                                                      const float* __restrict__ bias,
                                                      void* __restrict__ outp) {
    constexpr int NT  = (MODE == 0) ? 6 : 2;      // N / 256
    constexpr int CPX = (MODE == 0) ? 294 : 98;   // gridDim.x / 8

    const int o  = (blockIdx.x & 7) * CPX + (blockIdx.x >> 3);
    const int tm = o / NT, tn = o - tm * NT;

    const int tid = threadIdx.x, wave = tid >> 6, lane = tid & 63;

    __shared__ s16 lA[3][256 * 32];   // 48 KiB: [row][k-slot], 64 B rows
    __shared__ s16 lB[3][256 * 32];   // 48 KiB

    // staging: half-tile = 128 rows x 32 k = 8 KiB = 1 load-round (512 x 16 B)
    // LDS dest linear: lane -> row (wave*16 + lane>>2), slot (lane&3).
    // SOURCE k-block pre-swizzled: slot s of row r <- global block s^((r>>1)&3)
    const int rloc = wave * 16 + (lane >> 2);                  // row 0..127
    const int gran = (((lane & 3) ^ ((lane >> 3) & 3)) << 3);  // swizzled src k
    const s16* a_src[2];
    const s16* b_src[2];
#pragma unroll
    for (int i = 0; i < 2; ++i) {
        int row = i * 128 + rloc;
        if (MODE == 0) a_src[i] = x_row_ptr(A, tm * 256 + row) + gran;
        else           a_src[i] = A + (size_t)(tm * 256 + row) * 512 + gran;
        b_src[i] = Bt + (size_t)(tn * 256 + row) * 512 + gran;
    }

#define STAGE_A(buf, i)                                                         \
    do {                                                                        \
        __builtin_amdgcn_global_load_lds(                                       \
            (const __attribute__((address_space(1))) void*)a_src[i],            \
            (__attribute__((address_space(3))) void*)&lA[buf][(i) * 4096 + wave * 512], \
            16, 0, 0);                                                          \
        a_src[i] += 32;                                                         \
    } while (0)
#define STAGE_B(buf, i)                                                         \
    do {                                                                        \
        __builtin_amdgcn_global_load_lds(                                       \
            (const __attribute__((address_space(1))) void*)b_src[i],            \
            (__attribute__((address_space(3))) void*)&lB[buf][(i) * 4096 + wave * 512], \
            16, 0, 0);                                                          \
        b_src[i] += 32;                                                         \
    } while (0)

    floatx4 acc[8][4];
#pragma unroll
    for (int mt = 0; mt < 8; ++mt)
#pragma unroll
        for (int nt = 0; nt < 4; ++nt)
            acc[mt][nt] = (floatx4){0.f, 0.f, 0.f, 0.f};

    const int wm = wave & 1, wn = wave >> 1;     // A half, B quarter
    const int lm = lane & 15, quad = lane >> 4;
    // fragment read: k-block quad lives in LDS slot quad ^ ((lm>>1)&3)
    const int swz = ((quad ^ ((lm >> 1) & 3)) << 3);   // s16 offset in row

    // prologue: stage kt=0 and kt=1 (8 loads/wave), wait until kt0 resident
    STAGE_A(0, 0); STAGE_A(0, 1); STAGE_B(0, 0); STAGE_B(0, 1);
    STAGE_A(1, 0); STAGE_A(1, 1); STAGE_B(1, 0); STAGE_B(1, 1);
    asm volatile("s_waitcnt vmcnt(4)" ::: "memory");
    __builtin_amdgcn_s_barrier();
    __builtin_amdgcn_sched_barrier(0);

#pragma unroll
    for (int kt = 0; kt < 16; ++kt) {
        const int cur = kt % 3, nxt = (kt + 2) % 3;

        // ---------------- phase 0: mt 0..3 ----------------
        short8 bq[4], af[4];
#pragma unroll
        for (int nt = 0; nt < 4; ++nt)
            bq[nt] = *(const short8*)&lB[cur][(wn * 64 + nt * 16 + lm) * 32 + swz];
#pragma unroll
        for (int mt = 0; mt < 4; ++mt)
            af[mt] = *(const short8*)&lA[cur][(wm * 128 + mt * 16 + lm) * 32 + swz];
        if (kt < 14) { STAGE_A(nxt, 0); STAGE_A(nxt, 1); }

        __builtin_amdgcn_s_barrier();
        asm volatile("s_waitcnt lgkmcnt(0)" ::: "memory");
        __builtin_amdgcn_sched_barrier(0);

        __builtin_amdgcn_s_setprio(1);
#pragma unroll
        for (int mt = 0; mt < 4; ++mt)
#pragma unroll
            for (int nt = 0; nt < 4; ++nt)
                acc[mt][nt] = __builtin_amdgcn_mfma_f32_16x16x32_bf16(
                    af[mt], bq[nt], acc[mt][nt], 0, 0, 0);
        __builtin_amdgcn_s_setprio(0);
        __builtin_amdgcn_s_barrier();
        __builtin_amdgcn_sched_barrier(0);

        // ---------------- phase 1: mt 4..7 ----------------
        short8 ag[4];
#pragma unroll
        for (int mt = 0; mt < 4; ++mt)
            ag[mt] = *(const short8*)&lA[cur][(wm * 128 + (mt + 4) * 16 + lm) * 32 + swz];
        if (kt < 14) { STAGE_B(nxt, 0); STAGE_B(nxt, 1); }

        __builtin_amdgcn_s_barrier();
        asm volatile("s_waitcnt lgkmcnt(0)" ::: "memory");
        __builtin_amdgcn_sched_barrier(0);

        __builtin_amdgcn_s_setprio(1);
#pragma unroll
        for (int mt = 0; mt < 4; ++mt)
#pragma unroll
            for (int nt = 0; nt < 4; ++nt)
                acc[mt + 4][nt] = __builtin_amdgcn_mfma_f32_16x16x32_bf16(
                    ag[mt], bq[nt], acc[mt + 4][nt], 0, 0, 0);
        __builtin_amdgcn_s_setprio(0);

        if (kt < 14)       asm volatile("s_waitcnt vmcnt(4)" ::: "memory");
        else if (kt == 14) asm volatile("s_waitcnt vmcnt(0)" ::: "memory");
        if (kt != 15) {
            __builtin_amdgcn_s_barrier();
            __builtin_amdgcn_sched_barrier(0);
        }
    }
#undef STAGE_A
#undef STAGE_B

    // ---- epilogue: C/D layout col = lane&15, row = quad*4 + reg ----
    float bv[4];
#pragma unroll
    for (int nt = 0; nt < 4; ++nt)
        bv[nt] = bias[tn * 256 + wn * 64 + nt * 16 + lm];

#pragma unroll
    for (int mt = 0; mt < 8; ++mt) {
        int mbase = tm * 256 + wm * 128 + mt * 16 + quad * 4;
#pragma unroll
        for (int i = 0; i < 4; ++i) {
            int m = mbase + i;
            size_t rowoff;
            if (MODE == 1) {
                int win = m / 49, t = m - win * 49;
                int b = win >> 6, rem = win & 63, hb = rem >> 3, wb = rem & 7;
                int r = t / 7, c = t - r * 7;
                int n = (hb * 7 + r) * 56 + wb * 7 + c;
                rowoff = ((size_t)b * 3136 + n) * 512;
            } else {
                rowoff = (size_t)m * 1536;
            }
#pragma unroll
            for (int nt = 0; nt < 4; ++nt) {
                int coln = tn * 256 + wn * 64 + nt * 16 + lm;
                float v = acc[mt][nt][i] + bv[nt];
                if (MODE == 0) ((s16*)outp)[rowoff + coln] = f2bf(v);
                else           ((float*)outp)[rowoff + coln] = v;
            }
        }
    }
}

// --------- K2: per-(win,token) 8x8 head attention; 1 wave / row ----------
// qkv row m: [0,512)=q (h*64+d), [512,1024)=k, [1024,1536)=v
// out layout: attn[win*25088 + h*3136 + t*64 + d]  (== (m,512) rows for proj)
__global__ __launch_bounds__(256) void attn_kernel(const s16* __restrict__ qkv,
                                                   s16* __restrict__ attn) {
    const int tid = threadIdx.x, wave = tid >> 6, lane = tid & 63;
    const int m = blockIdx.x * 4 + wave;   // grid 25088 * 4 = 100352 exact

    __shared__ s16 sh[4][1536];
    s16* my = sh[wave];
    const s16* row = qkv + (size_t)m * 1536;
#pragma unroll
    for (int i = 0; i < 3; ++i)
        *(short8*)&my[i * 512 + lane * 8] = *(const short8*)&row[i * 512 + lane * 8];
    __syncthreads();

    const int h = lane >> 3, g = lane & 7;
    const s16* qs = my + h * 64;
    const s16* ks = my + 512 + g * 64;
    const s16* vs = my + 1024;

    // S[h][g] = (q_h . k_g) / 8 ; d-rotation by h avoids LDS bank conflicts
    float s = 0.f;
#pragma unroll
    for (int db = 0; db < 8; ++db) {
        int d0 = ((db + h) & 7) * 8;
        short8 q8 = *(const short8*)&qs[d0];
        short8 k8 = *(const short8*)&ks[d0];
#pragma unroll
        for (int j = 0; j < 8; ++j) s += bf2f(q8[j]) * bf2f(k8[j]);
    }
    s *= 0.125f;

    // softmax over g within each 8-lane group
    float mx = s;
    mx = fmaxf(mx, __shfl_xor(mx, 1));
    mx = fmaxf(mx, __shfl_xor(mx, 2));
    mx = fmaxf(mx, __shfl_xor(mx, 4));
    float p = __expf(s - mx);
    float sum = p;
    sum += __shfl_xor(sum, 1);
    sum += __shfl_xor(sum, 2);
    sum += __shfl_xor(sum, 4);
    p /= sum;

    // O[h][d0..d0+7], d0 = (lane&7)*8 ; p[h][gg] lives in lane h*8+gg
    float o[8];
#pragma unroll
    for (int j = 0; j < 8; ++j) o[j] = 0.f;
    const int dgrp = (lane & 7) * 8;
#pragma unroll
    for (int gg = 0; gg < 8; ++gg) {
        float pg = __shfl(p, h * 8 + gg);
        short8 v8 = *(const short8*)&vs[gg * 64 + dgrp];
#pragma unroll
        for (int j = 0; j < 8; ++j) o[j] += pg * bf2f(v8[j]);
    }

    int win = m / 49, t = m - win * 49;
    s16* dst = attn + (size_t)win * 25088 + h * 3136 + t * 64 + dgrp;
    short8 ob;
#pragma unroll
    for (int j = 0; j < 8; ++j) ob[j] = f2bf(o[j]);
    *(short8*)dst = ob;
}

extern "C" void kernel_launch(void* const* d_in, const int* in_sizes, int n_in,
                              void* d_out, int out_size, void* d_ws, size_t ws_size,
                              hipStream_t stream) {
    const float* x      = (const float*)d_in[0];
    const float* w_qkv  = (const float*)d_in[1];
    const float* b_qkv  = (const float*)d_in[2];
    const float* w_proj = (const float*)d_in[3];
    const float* b_proj = (const float*)d_in[4];

    char* ws = (char*)d_ws;
    // 102,760,448 B = 100352*512*2 ; 308,281,344 B = 100352*1536*2
    s16* xbf    = (s16*)ws;
    s16* qkv    = (s16*)(ws + 102760448ull);
    s16* attn   = (s16*)(ws + 102760448ull + 308281344ull);
    s16* wqkvT  = (s16*)(ws + 102760448ull + 308281344ull + 102760448ull);
    s16* wprojT = (s16*)(ws + 102760448ull + 308281344ull + 102760448ull + 1572864ull);

    cvt_kernel<<<25088, 256, 0, stream>>>(x, xbf);                       // 51.4M elems
    transpose_kernel<<<3072, 256, 0, stream>>>(w_qkv, wqkvT, 512, 1536);
    transpose_kernel<<<1024, 256, 0, stream>>>(w_proj, wprojT, 512, 512);
    gemm_kernel<0><<<392 * 6, 512, 0, stream>>>(xbf, wqkvT, b_qkv, qkv);
    attn_kernel<<<25088, 256, 0, stream>>>(qkv, attn);
    gemm_kernel<1><<<392 * 2, 512, 0, stream>>>(attn, wprojT, b_proj, d_out);
}